// Round 3
// baseline (655.462 us; speedup 1.0000x reference)
//
#include <hip/hip_runtime.h>
#include <hip/hip_bf16.h>
#include <hip/hip_fp16.h>

// B=2 H=16 S=2048 DK=128, fp32 in/out. out = [context (B,H,S,DK) | attn (B,H,S,S)]
constexpr int Bc = 2, Hc = 16, Sc = 2048, Dc = 128;
constexpr int BQ = 64;   // q-rows per block (4 waves x 16)
constexpr int KT = 32;   // k-cols per iteration
constexpr float SCALE = 0.08838834764831844f;  // 1/sqrt(128)

typedef _Float16 half8 __attribute__((ext_vector_type(8)));
typedef _Float16 half4v __attribute__((ext_vector_type(4)));
typedef float float4v __attribute__((ext_vector_type(4)));

// raw barrier: NO vmcnt drain (prefetch loads stay in flight across it)
#define SBAR() { __builtin_amdgcn_sched_barrier(0); \
                 __builtin_amdgcn_s_barrier(); \
                 __builtin_amdgcn_sched_barrier(0); }
#define LGKM0() { asm volatile("s_waitcnt lgkmcnt(0)" ::: "memory"); \
                  __builtin_amdgcn_sched_barrier(0); }

__global__ __launch_bounds__(256, 4)
void sdpa_kernel(const float* __restrict__ Q, const float* __restrict__ K,
                 const float* __restrict__ V, const float* __restrict__ M,
                 float* __restrict__ outC, float* __restrict__ outA)
{
    __shared__ __align__(16) _Float16 Kl[KT * Dc];    // 8KB, XOR-swizzled rows
    __shared__ __align__(16) _Float16 Vl[KT * Dc];    // 8KB, tr-subtiled
    __shared__ __align__(16) float    Pl[4][16 * 36]; // per-wave P transpose buf

    int bid = blockIdx.x;
    bid = (bid & 7) * 128 + (bid >> 3);   // XCD swizzle (1024 % 8 == 0, bijective)
    const int head = bid >> 5;
    const int q0   = (bid & 31) * BQ;

    const int tid  = threadIdx.x;
    const int wv   = tid >> 6;
    const int lane = tid & 63;
    const int g    = lane >> 4;
    const int c16  = lane & 15;
    const int qrow0 = q0 + wv * 16;

    const float* Qh = Q + (size_t)head * Sc * Dc;
    const float* Kh = K + (size_t)head * Sc * Dc;
    const float* Vh = V + (size_t)head * Sc * Dc;
    const float* Mh = M + (size_t)head * Sc * Sc;
    float* Ch = outC + (size_t)head * Sc * Dc;
    float* Ah = outA + (size_t)head * Sc * Sc;

    // ---- Q A-fragments (fp16): rows qrow0+c16, k-elems c*32 + g*8 + j ----
    half8 aq[4];
    {
        const float* qp = Qh + (size_t)(qrow0 + c16) * Dc + g * 8;
        #pragma unroll
        for (int c = 0; c < 4; ++c) {
            float4v f0 = *(const float4v*)(qp + c * 32);
            float4v f1 = *(const float4v*)(qp + c * 32 + 4);
            half8 h;
            #pragma unroll
            for (int j = 0; j < 4; ++j) { h[j] = (_Float16)f0[j]; h[4 + j] = (_Float16)f1[j]; }
            aq[c] = h;
        }
    }

    // staging coords: thread -> K/V row kr, d-chunk dc0
    const int kr  = tid >> 3;
    const int dc0 = (tid & 7) * 16;

    float4v kf[4], vf[4];          // prefetch registers (live across barriers)

    auto loadK = [&](int kb) {
        const float* kp = Kh + (size_t)(kb + kr) * Dc + dc0;
        #pragma unroll
        for (int i = 0; i < 4; ++i) kf[i] = *(const float4v*)(kp + 4 * i);
    };
    auto loadV = [&](int kb) {
        const float* vp = Vh + (size_t)(kb + kr) * Dc + dc0;
        #pragma unroll
        for (int i = 0; i < 4; ++i) vf[i] = *(const float4v*)(vp + 4 * i);
    };
    auto writeK = [&]() {
        half8 h0, h1;
        #pragma unroll
        for (int j = 0; j < 4; ++j) {
            h0[j] = (_Float16)kf[0][j]; h0[4 + j] = (_Float16)kf[1][j];
            h1[j] = (_Float16)kf[2][j]; h1[4 + j] = (_Float16)kf[3][j];
        }
        const int sw = (kr & 7) << 3;
        *(half8*)&Kl[kr * Dc + ((dc0    ) ^ sw)] = h0;
        *(half8*)&Kl[kr * Dc + ((dc0 + 8) ^ sw)] = h1;
    };
    auto writeV = [&]() {
        half8 h0, h1;
        #pragma unroll
        for (int j = 0; j < 4; ++j) {
            h0[j] = (_Float16)vf[0][j]; h0[4 + j] = (_Float16)vf[1][j];
            h1[j] = (_Float16)vf[2][j]; h1[4 + j] = (_Float16)vf[3][j];
        }
        const int kq = kr >> 2;
        const int sub = ((tid & 7) * 2 + (kq & 1)) * 4 + (kq >> 1);
        const int base = sub * 64 + (kr & 3) * 16;
        *(half8*)&Vl[base]     = h0;
        *(half8*)&Vl[base + 8] = h1;
    };

    auto qk = [&](float4v accS[2]) {
        #pragma unroll
        for (int sub = 0; sub < 2; ++sub) {
            const int krow = sub * 16 + c16;
            const _Float16* rp = &Kl[krow * Dc];
            const int sw = (krow & 7) << 3;
            #pragma unroll
            for (int c = 0; c < 4; ++c) {
                half8 bk = *(const half8*)&rp[(c * 32 + g * 8) ^ sw];
                accS[sub] = __builtin_amdgcn_mfma_f32_16x16x32_f16(aq[c], bk, accS[sub], 0, 0, 0);
            }
        }
    };

    // ================= Pass A: row sums of exp(scores) =================
    float psum[4] = {0.f, 0.f, 0.f, 0.f};
    loadK(0);
    for (int kb = 0; kb < Sc; kb += KT) {
        SBAR();                       // all waves done reading previous tile
        writeK();                     // counted vmcnt wait on kf at first use
        if (kb + KT < Sc) loadK(kb + KT);   // stays in flight across barrier
        LGKM0();                      // LDS writes visible
        SBAR();
        float4v accS[2] = {{0,0,0,0},{0,0,0,0}};
        qk(accS);
        #pragma unroll
        for (int sub = 0; sub < 2; ++sub)
            #pragma unroll
            for (int r = 0; r < 4; ++r)
                psum[r] += __expf(accS[sub][r] * SCALE);
    }

    // prefetch pass-B kb=0 while reducing
    loadK(0); loadV(0);
    float4v m0, m1;
    auto loadM = [&](int kb) {
        const float* mp = Mh + (size_t)(qrow0 + c16) * Sc + kb + g * 8;
        m0 = *(const float4v*)mp;
        m1 = *(const float4v*)(mp + 4);
    };
    loadM(0);

    #pragma unroll
    for (int m = 1; m < 16; m <<= 1)
        #pragma unroll
        for (int r = 0; r < 4; ++r)
            psum[r] += __shfl_xor(psum[r], m, 64);
    float invl[4];
    #pragma unroll
    for (int r = 0; r < 4; ++r) invl[r] = 1.0f / psum[r];

    // ================= Pass B =================
    float4v accC[8];
    #pragma unroll
    for (int d = 0; d < 8; ++d) accC[d] = (float4v){0, 0, 0, 0};

    const unsigned int vbase = (unsigned int)(uintptr_t)(&Vl[0]);
    float* pw = &Pl[wv][0];

    // PV tr-read pipeline: 4 static reg slots (mod-4), counted lgkm waits
    half4v trA[4], trB[4];
#define TRI(D) { unsigned int a_ = vbase + (D) * 1024 + lane * 8; \
    asm volatile("ds_read_b64_tr_b16 %0, %2\n\t" \
                 "ds_read_b64_tr_b16 %1, %2 offset:512" \
                 : "=&v"(trA[(D) & 3]), "=&v"(trB[(D) & 3]) : "v"(a_)); }
#define PVM(D, N) { \
    asm volatile("s_waitcnt lgkmcnt(" #N ")" ::: "memory"); \
    __builtin_amdgcn_sched_barrier(0); \
    half8 bv; \
    for (int j = 0; j < 4; ++j) { bv[j] = trA[(D) & 3][j]; bv[4 + j] = trB[(D) & 3][j]; } \
    accC[D] = __builtin_amdgcn_mfma_f32_16x16x32_f16(ap, bv, accC[D], 0, 0, 0); }

    for (int kb = 0; kb < Sc; kb += KT) {
        SBAR();
        writeK(); writeV();
        if (kb + KT < Sc) { loadK(kb + KT); loadV(kb + KT); }
        LGKM0();
        SBAR();

        float4v accS[2] = {{0,0,0,0},{0,0,0,0}};
        qk(accS);

        // normalized p -> per-wave LDS transpose buffer (C layout write)
        #pragma unroll
        for (int sub = 0; sub < 2; ++sub)
            #pragma unroll
            for (int r = 0; r < 4; ++r) {
                float p = __expf(accS[sub][r] * SCALE) * invl[r];
                pw[(g * 4 + r) * 36 + sub * 16 + c16] = p;
            }
        LGKM0();

        // read back in A layout: row c16, cols kb + g*8 .. +7
        float4v p0 = *(const float4v*)&pw[c16 * 36 + g * 8];
        float4v p1 = *(const float4v*)&pw[c16 * 36 + g * 8 + 4];

        // vectorized attn store (never waited on — no drain in loop)
        float* as_ = &Ah[(size_t)(qrow0 + c16) * Sc + kb + g * 8];
        *(float4v*)as_       = p0;
        *(float4v*)(as_ + 4) = p1;

        // blend with prefetched M, convert to fp16 A-fragment
        half8 ap;
        #pragma unroll
        for (int j = 0; j < 4; ++j) {
            ap[j]     = (_Float16)(0.7f * p0[j] + 0.3f * m0[j]);
            ap[4 + j] = (_Float16)(0.7f * p1[j] + 0.3f * m1[j]);
        }
        if (kb + KT < Sc) loadM(kb + KT);

        // ---- PV: tr-reads pipelined 3-pairs-deep, counted lgkm ----
        TRI(0) TRI(1)
        TRI(2) PVM(0, 4)
        TRI(3) PVM(1, 4)
        TRI(4) PVM(2, 4)
        TRI(5) PVM(3, 4)
        TRI(6) PVM(4, 4)
        TRI(7) PVM(5, 4)
        PVM(6, 2)
        PVM(7, 0)
    }

    // ================= epilogue: context =================
    #pragma unroll
    for (int d = 0; d < 8; ++d)
        #pragma unroll
        for (int r = 0; r < 4; ++r)
            Ch[(size_t)(qrow0 + g * 4 + r) * Dc + d * 16 + c16] = accC[d][r];
}

extern "C" void kernel_launch(void* const* d_in, const int* in_sizes, int n_in,
                              void* d_out, int out_size, void* d_ws, size_t ws_size,
                              hipStream_t stream) {
    const float* Q = (const float*)d_in[0];
    const float* K = (const float*)d_in[1];
    const float* V = (const float*)d_in[2];
    const float* M = (const float*)d_in[4];   // d_in[3] = attn_mask (unused)
    float* outC = (float*)d_out;
    float* outA = outC + (size_t)Bc * Hc * Sc * Dc;

    const int grid = Bc * Hc * (Sc / BQ);  // 1024
    sdpa_kernel<<<dim3(grid), dim3(256), 0, stream>>>(Q, K, V, M, outC, outA);
}

// Round 4
// 442.595 us; speedup vs baseline: 1.4810x; 1.4810x over previous
//
#include <hip/hip_runtime.h>
#include <hip/hip_bf16.h>
#include <hip/hip_fp16.h>

// B=2 H=16 S=2048 DK=128, fp32 in/out. out = [context (B,H,S,DK) | attn (B,H,S,S)]
constexpr int Bc = 2, Hc = 16, Sc = 2048, Dc = 128;
constexpr int BQ = 64;   // q-rows per block (4 waves x 16)
constexpr int KT = 32;   // k-cols per iteration
constexpr int NT = Sc / KT;  // 64
constexpr float SCALE = 0.08838834764831844f;  // 1/sqrt(128)

typedef _Float16 half8 __attribute__((ext_vector_type(8)));
typedef _Float16 half4v __attribute__((ext_vector_type(4)));
typedef float float4v __attribute__((ext_vector_type(4)));

// raw barrier: NO vmcnt drain (prefetch loads stay in flight across it)
#define SBAR() { __builtin_amdgcn_sched_barrier(0); \
                 __builtin_amdgcn_s_barrier(); \
                 __builtin_amdgcn_sched_barrier(0); }
#define LGKM0() { asm volatile("s_waitcnt lgkmcnt(0)" ::: "memory"); \
                  __builtin_amdgcn_sched_barrier(0); }

__global__ __launch_bounds__(256, 2)
void sdpa_kernel(const float* __restrict__ Q, const float* __restrict__ K,
                 const float* __restrict__ V, const float* __restrict__ M,
                 float* __restrict__ outC, float* __restrict__ outA)
{
    __shared__ __align__(16) _Float16 Kl[2][KT * Dc];  // 2x8KB, XOR-swizzled rows
    __shared__ __align__(16) _Float16 Vl[2][KT * Dc];  // 2x8KB, tr-subtiled
    __shared__ __align__(16) float    Pl[4][16 * 36];  // per-wave P transpose buf

    int bid = blockIdx.x;
    bid = (bid & 7) * 128 + (bid >> 3);   // XCD swizzle (1024 % 8 == 0, bijective)
    const int head = bid >> 5;
    const int q0   = (bid & 31) * BQ;

    const int tid  = threadIdx.x;
    const int wv   = tid >> 6;
    const int lane = tid & 63;
    const int g    = lane >> 4;
    const int c16  = lane & 15;
    const int qrow0 = q0 + wv * 16;

    const float* Qh = Q + (size_t)head * Sc * Dc;
    const float* Kh = K + (size_t)head * Sc * Dc;
    const float* Vh = V + (size_t)head * Sc * Dc;
    const float* Mh = M + (size_t)head * Sc * Sc;
    float* Ch = outC + (size_t)head * Sc * Dc;
    float* Ah = outA + (size_t)head * Sc * Sc;

    // ---- Q A-fragments (fp16): rows qrow0+c16, k-elems c*32 + g*8 + j ----
    half8 aq[4];
    {
        const float* qp = Qh + (size_t)(qrow0 + c16) * Dc + g * 8;
        #pragma unroll
        for (int c = 0; c < 4; ++c) {
            float4v f0 = *(const float4v*)(qp + c * 32);
            float4v f1 = *(const float4v*)(qp + c * 32 + 4);
            half8 h;
            #pragma unroll
            for (int j = 0; j < 4; ++j) { h[j] = (_Float16)f0[j]; h[4 + j] = (_Float16)f1[j]; }
            aq[c] = h;
        }
    }

    // staging coords: thread -> K/V row kr, d-chunk dc0
    const int kr  = tid >> 3;
    const int dc0 = (tid & 7) * 16;

    float4v kf[4], vf[4];          // prefetch registers (live across one iteration)

    auto loadK = [&](int t) {
        const float* kp = Kh + (size_t)(t * KT + kr) * Dc + dc0;
        #pragma unroll
        for (int i = 0; i < 4; ++i) kf[i] = *(const float4v*)(kp + 4 * i);
    };
    auto loadV = [&](int t) {
        const float* vp = Vh + (size_t)(t * KT + kr) * Dc + dc0;
        #pragma unroll
        for (int i = 0; i < 4; ++i) vf[i] = *(const float4v*)(vp + 4 * i);
    };
    auto writeK = [&](int buf) {
        half8 h0, h1;
        #pragma unroll
        for (int j = 0; j < 4; ++j) {
            h0[j] = (_Float16)kf[0][j]; h0[4 + j] = (_Float16)kf[1][j];
            h1[j] = (_Float16)kf[2][j]; h1[4 + j] = (_Float16)kf[3][j];
        }
        const int sw = (kr & 7) << 3;
        *(half8*)&Kl[buf][kr * Dc + ((dc0    ) ^ sw)] = h0;
        *(half8*)&Kl[buf][kr * Dc + ((dc0 + 8) ^ sw)] = h1;
    };
    auto writeV = [&](int buf) {
        half8 h0, h1;
        #pragma unroll
        for (int j = 0; j < 4; ++j) {
            h0[j] = (_Float16)vf[0][j]; h0[4 + j] = (_Float16)vf[1][j];
            h1[j] = (_Float16)vf[2][j]; h1[4 + j] = (_Float16)vf[3][j];
        }
        const int kq = kr >> 2;
        const int sub = ((tid & 7) * 2 + (kq & 1)) * 4 + (kq >> 1);
        const int base = sub * 64 + (kr & 3) * 16;
        *(half8*)&Vl[buf][base]     = h0;
        *(half8*)&Vl[buf][base + 8] = h1;
    };

    auto qk = [&](int buf, float4v accS[2]) {
        #pragma unroll
        for (int sub = 0; sub < 2; ++sub) {
            const int krow = sub * 16 + c16;
            const _Float16* rp = &Kl[buf][krow * Dc];
            const int sw = (krow & 7) << 3;
            #pragma unroll
            for (int c = 0; c < 4; ++c) {
                half8 bk = *(const half8*)&rp[(c * 32 + g * 8) ^ sw];
                accS[sub] = __builtin_amdgcn_mfma_f32_16x16x32_f16(aq[c], bk, accS[sub], 0, 0, 0);
            }
        }
    };

    // ================= Pass A: row sums of exp(scores) =================
    float psum[4] = {0.f, 0.f, 0.f, 0.f};
    loadK(0);
    writeK(0);          // compiler inserts vmcnt wait at cvt of kf
    loadK(1);
    LGKM0(); SBAR();
    for (int t = 0; t < NT; ++t) {
        const int cur = t & 1;
        float4v accS[2] = {{0,0,0,0},{0,0,0,0}};
        qk(cur, accS);
        #pragma unroll
        for (int sub = 0; sub < 2; ++sub)
            #pragma unroll
            for (int r = 0; r < 4; ++r)
                psum[r] += __expf(accS[sub][r] * SCALE);
        if (t + 1 < NT) {
            writeK(cur ^ 1);
            if (t + 2 < NT) loadK(t + 2);
        }
        LGKM0(); SBAR();
    }

    #pragma unroll
    for (int m = 1; m < 16; m <<= 1)
        #pragma unroll
        for (int r = 0; r < 4; ++r)
            psum[r] += __shfl_xor(psum[r], m, 64);
    float invl[4];
    #pragma unroll
    for (int r = 0; r < 4; ++r) invl[r] = 1.0f / psum[r];

    // ================= Pass B =================
    float4v accC[8];
    #pragma unroll
    for (int d = 0; d < 8; ++d) accC[d] = (float4v){0, 0, 0, 0};

    float4v m0, m1;
    auto loadM = [&](int t) {
        const float* mp = Mh + (size_t)(qrow0 + c16) * Sc + t * KT + g * 8;
        m0 = *(const float4v*)mp;
        m1 = *(const float4v*)(mp + 4);
    };

    // prologue: fill buf0, prefetch tile1 + M0
    loadK(0); loadV(0);
    writeK(0); writeV(0);
    loadK(1); loadV(1);
    loadM(0);
    LGKM0(); SBAR();

    const unsigned int vbase0 = (unsigned int)(uintptr_t)(&Vl[0][0]);
    float* pw = &Pl[wv][0];

    // PV tr-read pipeline: 4 static reg slots (mod-4), counted lgkm waits
    half4v trA[4], trB[4];
#define TRI(D) { unsigned int a_ = vb + (D) * 1024 + lane * 8; \
    asm volatile("ds_read_b64_tr_b16 %0, %2\n\t" \
                 "ds_read_b64_tr_b16 %1, %2 offset:512" \
                 : "=&v"(trA[(D) & 3]), "=&v"(trB[(D) & 3]) : "v"(a_)); }
#define PVM(D, N) { \
    asm volatile("s_waitcnt lgkmcnt(" #N ")" ::: "memory"); \
    __builtin_amdgcn_sched_barrier(0); \
    half8 bv; \
    for (int j = 0; j < 4; ++j) { bv[j] = trA[(D) & 3][j]; bv[4 + j] = trB[(D) & 3][j]; } \
    accC[D] = __builtin_amdgcn_mfma_f32_16x16x32_f16(ap, bv, accC[D], 0, 0, 0); }

    for (int t = 0; t < NT; ++t) {
        const int cur = t & 1;

        float4v accS[2] = {{0,0,0,0},{0,0,0,0}};
        qk(cur, accS);

        // normalized p -> per-wave LDS transpose buffer (C layout write)
        #pragma unroll
        for (int sub = 0; sub < 2; ++sub)
            #pragma unroll
            for (int r = 0; r < 4; ++r) {
                float p = __expf(accS[sub][r] * SCALE) * invl[r];
                pw[(g * 4 + r) * 36 + sub * 16 + c16] = p;
            }
        LGKM0();

        // read back in A layout: row c16, cols t*KT + g*8 .. +7
        float4v p0 = *(const float4v*)&pw[c16 * 36 + g * 8];
        float4v p1 = *(const float4v*)&pw[c16 * 36 + g * 8 + 4];

        // vectorized attn store (never waited on — no vmcnt drain in loop)
        float* as_ = &Ah[(size_t)(qrow0 + c16) * Sc + t * KT + g * 8];
        *(float4v*)as_       = p0;
        *(float4v*)(as_ + 4) = p1;

        // blend with prefetched M, convert to fp16 A-fragment
        half8 ap;
        #pragma unroll
        for (int j = 0; j < 4; ++j) {
            ap[j]     = (_Float16)(0.7f * p0[j] + 0.3f * m0[j]);
            ap[4 + j] = (_Float16)(0.7f * p1[j] + 0.3f * m1[j]);
        }
        if (t + 1 < NT) loadM(t + 1);

        // ---- PV: tr-reads pipelined 3-pairs-deep, counted lgkm ----
        LGKM0();   // zero the lgkm baseline for counted waits
        const unsigned int vb = vbase0 + (unsigned int)(cur * (KT * Dc * 2));
        TRI(0) TRI(1)
        TRI(2) PVM(0, 4)
        TRI(3) PVM(1, 4)
        TRI(4) PVM(2, 4)
        TRI(5) PVM(3, 4)
        TRI(6) PVM(4, 4)
        TRI(7) PVM(5, 4)
        PVM(6, 2)
        PVM(7, 0)

        // stage next tile into the other buffer; issue loads for t+2
        if (t + 1 < NT) {
            writeK(cur ^ 1); writeV(cur ^ 1);
            if (t + 2 < NT) { loadK(t + 2); loadV(t + 2); }
        }
        LGKM0(); SBAR();
    }

    // ================= epilogue: context =================
    #pragma unroll
    for (int d = 0; d < 8; ++d)
        #pragma unroll
        for (int r = 0; r < 4; ++r)
            Ch[(size_t)(qrow0 + g * 4 + r) * Dc + d * 16 + c16] = accC[d][r];
}

extern "C" void kernel_launch(void* const* d_in, const int* in_sizes, int n_in,
                              void* d_out, int out_size, void* d_ws, size_t ws_size,
                              hipStream_t stream) {
    const float* Q = (const float*)d_in[0];
    const float* K = (const float*)d_in[1];
    const float* V = (const float*)d_in[2];
    const float* M = (const float*)d_in[4];   // d_in[3] = attn_mask (unused)
    float* outC = (float*)d_out;
    float* outA = outC + (size_t)Bc * Hc * Sc * Dc;

    const int grid = Bc * Hc * (Sc / BQ);  // 1024
    sdpa_kernel<<<dim3(grid), dim3(256), 0, stream>>>(Q, K, V, M, outC, outA);
}